// Round 1
// baseline (124.436 us; speedup 1.0000x reference)
//
#include <hip/hip_runtime.h>
#include <math.h>

// Problem constants (from reference setup_inputs):
//   E=3, B=4096, D=1024, M=5, N=256
// loss = mean(sum(feature*gt,-1)) + 0.1 * (sum_e OT_e * 2) / E
#define NSIM_BLOCKS 48          // 3 e * 16 chunks of 16 rows
#define NDOT_BLOCKS 512
#define TOTAL_F4 3145728        // 3*4096*1024 / 4

// Kernel 1: blocks [0,48) compute normalized sim[e][m][n] into ws_sim;
//           blocks [48,560) compute partial sums of feature.gt into ws_partials.
__global__ __launch_bounds__(256) void fused_main(
    const float4* __restrict__ f4, const float4* __restrict__ g4,
    const float* __restrict__ gt_local, const float* __restrict__ feat_local,
    float* __restrict__ ws_partials, float* __restrict__ ws_sim)
{
    __shared__ float s_sh[5 * 1024];   // 20 KB: gt_local rows for one e
    __shared__ float rns_sh[5];
    __shared__ float red_sh[4];
    const int tid = threadIdx.x;
    const int lane = tid & 63;
    const int wid = tid >> 6;

    if (blockIdx.x < NSIM_BLOCKS) {
        // ---- similarity blocks ----
        const int b = blockIdx.x;
        const int e = b >> 4;          // 0..2
        const int chunk = b & 15;      // 0..15  (16 n-rows each)
        const float* sbase = gt_local + e * 5 * 1024;
        for (int idx = tid; idx < 5120; idx += 256) s_sh[idx] = sbase[idx];
        __syncthreads();
        // row norms of s (wave m%4 handles row m)
        for (int m = wid; m < 5; m += 4) {
            float acc = 0.f;
            #pragma unroll
            for (int k = 0; k < 16; ++k) {
                float v = s_sh[m * 1024 + lane + 64 * k];
                acc += v * v;
            }
            #pragma unroll
            for (int o = 32; o; o >>= 1) acc += __shfl_xor(acc, o);
            if (lane == 0) rns_sh[m] = 1.f / fmaxf(sqrtf(acc), 1e-12f);
        }
        __syncthreads();
        // wave-per-t-row: 4 waves * 4 rows = 16 rows per block
        for (int rr = 0; rr < 4; ++rr) {
            const int n = chunk * 16 + wid * 4 + rr;
            const float* trow = feat_local + (e * 256 + n) * 1024;
            float a0 = 0.f, a1 = 0.f, a2 = 0.f, a3 = 0.f, a4 = 0.f, at = 0.f;
            #pragma unroll
            for (int k = 0; k < 16; ++k) {
                const int d = lane + 64 * k;          // coalesced per wave
                const float tv = trow[d];
                at += tv * tv;
                a0 += tv * s_sh[d];
                a1 += tv * s_sh[1024 + d];
                a2 += tv * s_sh[2048 + d];
                a3 += tv * s_sh[3072 + d];
                a4 += tv * s_sh[4096 + d];
            }
            #pragma unroll
            for (int o = 32; o; o >>= 1) {
                at += __shfl_xor(at, o);
                a0 += __shfl_xor(a0, o);
                a1 += __shfl_xor(a1, o);
                a2 += __shfl_xor(a2, o);
                a3 += __shfl_xor(a3, o);
                a4 += __shfl_xor(a4, o);
            }
            if (lane == 0) {
                const float rnt = 1.f / fmaxf(sqrtf(at), 1e-12f);
                float* dst = ws_sim + e * 5 * 256 + n;
                dst[0]    = a0 * rns_sh[0] * rnt;
                dst[256]  = a1 * rns_sh[1] * rnt;
                dst[512]  = a2 * rns_sh[2] * rnt;
                dst[768]  = a3 * rns_sh[3] * rnt;
                dst[1024] = a4 * rns_sh[4] * rnt;
            }
        }
    } else {
        // ---- streaming dot-product blocks ----
        const int d = blockIdx.x - NSIM_BLOCKS;
        float acc = 0.f;
        const int stride = NDOT_BLOCKS * 256;
        for (int i = d * 256 + tid; i < TOTAL_F4; i += stride) {
            const float4 a = f4[i];
            const float4 b = g4[i];
            acc += a.x * b.x + a.y * b.y + a.z * b.z + a.w * b.w;
        }
        #pragma unroll
        for (int o = 32; o; o >>= 1) acc += __shfl_xor(acc, o);
        if (lane == 0) red_sh[wid] = acc;
        __syncthreads();
        if (tid == 0)
            ws_partials[d] = red_sh[0] + red_sh[1] + red_sh[2] + red_sh[3];
    }
}

// Kernel 2: waves 0..2 run Sinkhorn per extractor (lane owns 4 columns of the
// 5x256 K matrix; all reductions are 64-lane butterflies). Wave 3 reduces the
// 512 dot partials in double. Thread 0 combines.
__global__ __launch_bounds__(256) void finalize_kernel(
    const float* __restrict__ ws_partials, const float* __restrict__ ws_sim,
    float* __restrict__ out)
{
    __shared__ float ot_sh[3];
    __shared__ double g_sh;
    const int tid = threadIdx.x;
    const int lane = tid & 63;
    const int wid = tid >> 6;

    if (wid < 3) {
        const int e = wid;
        float K[5][4], S[5][4];
        #pragma unroll
        for (int m = 0; m < 5; ++m)
            #pragma unroll
            for (int j = 0; j < 4; ++j) {
                const float s = ws_sim[(e * 5 + m) * 256 + lane + 64 * j];
                S[m][j] = s;
                K[m][j] = expf(-(1.0f - s) / 0.1f);   // SINK_EPS = 0.1
            }
        float r[5] = {1.f, 1.f, 1.f, 1.f, 1.f};
        float c[4] = {1.f, 1.f, 1.f, 1.f};
        float err;
        int it = 0;
        do {
            float r0[5];
            #pragma unroll
            for (int m = 0; m < 5; ++m) r0[m] = r[m];
            #pragma unroll
            for (int m = 0; m < 5; ++m) {
                float p = K[m][0] * c[0] + K[m][1] * c[1] +
                          K[m][2] * c[2] + K[m][3] * c[3];
                #pragma unroll
                for (int o = 32; o; o >>= 1) p += __shfl_xor(p, o);
                r[m] = 0.2f / p;                      // u = 1/M = 1/5
            }
            #pragma unroll
            for (int j = 0; j < 4; ++j) {
                const float q = K[0][j] * r[0] + K[1][j] * r[1] +
                                K[2][j] * r[2] + K[3][j] * r[3] +
                                K[4][j] * r[4];
                c[j] = (1.0f / 256.0f) / q;           // v = 1/N
            }
            err = (fabsf(r[0] - r0[0]) + fabsf(r[1] - r0[1]) +
                   fabsf(r[2] - r0[2]) + fabsf(r[3] - r0[3]) +
                   fabsf(r[4] - r0[4])) * 0.2f;       // mean over M=5
            ++it;
        } while (it < 100 && err >= 0.01f);           // MAX_ITERS, THRESH

        float ot = 0.f;
        #pragma unroll
        for (int m = 0; m < 5; ++m)
            #pragma unroll
            for (int j = 0; j < 4; ++j)
                ot += r[m] * c[j] * K[m][j] * S[m][j];
        #pragma unroll
        for (int o = 32; o; o >>= 1) ot += __shfl_xor(ot, o);
        if (lane == 0) ot_sh[e] = ot;
    } else {
        // reduce 512 dot partials in double
        double acc = 0.0;
        #pragma unroll
        for (int k = 0; k < 8; ++k) acc += (double)ws_partials[lane + 64 * k];
        #pragma unroll
        for (int o = 32; o; o >>= 1) acc += __shfl_xor(acc, o);
        if (lane == 0) g_sh = acc;
    }
    __syncthreads();
    if (tid == 0) {
        const float loss_global = (float)(g_sh / 12288.0);   // mean over E*B
        const float loss_local = (ot_sh[0] + ot_sh[1] + ot_sh[2]) * 2.0f / 3.0f;
        out[0] = loss_global + 0.1f * loss_local;
    }
}

extern "C" void kernel_launch(void* const* d_in, const int* in_sizes, int n_in,
                              void* d_out, int out_size, void* d_ws, size_t ws_size,
                              hipStream_t stream) {
    const float4* f4 = (const float4*)d_in[0];          // feature  [3,4096,1024]
    const float4* g4 = (const float4*)d_in[1];          // gt       [3,4096,1024]
    const float* gt_local = (const float*)d_in[2];      // [3,5,1024]
    const float* feat_local = (const float*)d_in[3];    // [3,256,1024]
    float* ws_partials = (float*)d_ws;                  // 512 floats
    float* ws_sim = ws_partials + NDOT_BLOCKS;          // 3*5*256 floats
    float* out = (float*)d_out;

    hipLaunchKernelGGL(fused_main, dim3(NSIM_BLOCKS + NDOT_BLOCKS), dim3(256), 0,
                       stream, f4, g4, gt_local, feat_local, ws_partials, ws_sim);
    hipLaunchKernelGGL(finalize_kernel, dim3(1), dim3(256), 0, stream,
                       ws_partials, ws_sim, out);
}